// Round 5
// baseline (309.265 us; speedup 1.0000x reference)
//
#include <hip/hip_runtime.h>
#include <stdint.h>

// ============================================================================
// HyperPatch: bit-exact jax.random.categorical (threefry2x32, partitionable)
// + 3x3x3 patch gather.
//
// categorical with 0/1 probs == argmax over allowed s of (threefry_bits>>9),
// tie -> lowest flat index. Slot key: ((val23+1)<<18)|(S-1-s); u64 atomicMax.
//
// Round-5: k_sample_list was VALU-bound at ~153 instr/candidate (u64 max chain
// + fat codegen). Now: inline-asm 2-chain threefry core (exactly 3 instr/round)
// + all-32-bit (vmax,smin) epilogue; u64 only at the final per-wave atomic.
//
// ws layout: ctr   @0      int, stride 16 u32 (64B/counter), 8 counters
//            slots @1024   u64[1024]
//            lists @16384  u32[4*S_VOL]:
//              regA(b)=lists+b*2S: posb front, negb back
//              regB(b)=regA+S:     pos  front, neg  back
// ============================================================================

#define S_VOL   262144          // 64*64*64
#define VALID_N 238328          // 62^3
#define OUT_N   221184          // 2*8*1*2*32*8*27
#define CTR(b, set) (((b) * 4 + (set)) * 16)
#define SINF 0xFFFFFFFFu

struct Keys { uint32_t k[4][2]; };

// ---------------- threefry2x32 (reference C version, host + cold paths) -----
#define TF_ROUND(r) { x0 += x1; x1 = (x1 << (r)) | (x1 >> (32 - (r))); x1 ^= x0; }

__host__ __device__ static inline void tf2x32(uint32_t k0, uint32_t k1,
                                              uint32_t& x0, uint32_t& x1) {
  uint32_t ks2 = k0 ^ k1 ^ 0x1BD11BDAu;
  x0 += k0; x1 += k1;
  TF_ROUND(13) TF_ROUND(15) TF_ROUND(26) TF_ROUND(6)
  x0 += k1;  x1 += ks2 + 1u;
  TF_ROUND(17) TF_ROUND(29) TF_ROUND(16) TF_ROUND(24)
  x0 += ks2; x1 += k0 + 2u;
  TF_ROUND(13) TF_ROUND(15) TF_ROUND(26) TF_ROUND(6)
  x0 += k0;  x1 += k1 + 3u;
  TF_ROUND(17) TF_ROUND(29) TF_ROUND(16) TF_ROUND(24)
  x0 += k1;  x1 += ks2 + 4u;
  TF_ROUND(13) TF_ROUND(15) TF_ROUND(26) TF_ROUND(6)
  x0 += ks2; x1 += k0 + 5u;
}

struct TFC { uint32_t x0i, sk1, a1,b1,a2,b2,a3,b3,a4,b4,a5,b5; };

__device__ static inline uint32_t tf_hash_c(uint32_t s, const TFC& c) {
  uint32_t x0 = c.x0i, x1 = s + c.sk1;
  #define RR(r) { x0 += x1; x1 = (x1 << (r)) | (x1 >> (32 - (r))); x1 ^= x0; }
  RR(13) RR(15) RR(26) RR(6)   x0 += c.a1; x1 += c.b1;
  RR(17) RR(29) RR(16) RR(24)  x0 += c.a2; x1 += c.b2;
  RR(13) RR(15) RR(26) RR(6)   x0 += c.a3; x1 += c.b3;
  RR(17) RR(29) RR(16) RR(24)  x0 += c.a4; x1 += c.b4;
  RR(13) RR(15) RR(26) RR(6)   x0 += c.a5; x1 += c.b5;
  #undef RR
  return x0 ^ x1;
}

// 2-chain asm round: rotl(x,r) == v_alignbit_b32(x,x,32-r). Exactly 6 instr.
#define RND2(S2) asm("v_add_u32 %0, %0, %1\n\t"                    \
                     "v_add_u32 %2, %2, %3\n\t"                    \
                     "v_alignbit_b32 %1, %1, %1, " #S2 "\n\t"      \
                     "v_alignbit_b32 %3, %3, %3, " #S2 "\n\t"      \
                     "v_xor_b32 %1, %1, %0\n\t"                    \
                     "v_xor_b32 %3, %3, %2"                        \
                     : "+v"(x0a), "+v"(x1a), "+v"(x0b), "+v"(x1b))
// rot {13,15,26,6} -> shifts {19,17,6,26}; rot {17,29,16,24} -> {15,3,16,8}
#define GRP_A RND2(19); RND2(17); RND2(6); RND2(26)
#define GRP_B RND2(15); RND2(3); RND2(16); RND2(8)

#define HASH2(sa, sb, ba, bb) {                                         \
  uint32_t x0a = tc.x0i, x1a = (sa) + tc.sk1;                           \
  uint32_t x0b = tc.x0i, x1b = (sb) + tc.sk1;                           \
  GRP_A; x0a += tc.a1; x1a += tc.b1; x0b += tc.a1; x1b += tc.b1;        \
  GRP_B; x0a += tc.a2; x1a += tc.b2; x0b += tc.a2; x1b += tc.b2;        \
  GRP_A; x0a += tc.a3; x1a += tc.b3; x0b += tc.a3; x1b += tc.b3;        \
  GRP_B; x0a += tc.a4; x1a += tc.b4; x0b += tc.a4; x1b += tc.b4;        \
  GRP_A; x0a += tc.a5; x1a += tc.b5; x0b += tc.a5; x1b += tc.b5;        \
  ba = x0a ^ x1a; bb = x0b ^ x1b;                                       \
}

// 32-bit lexicographic running-max update: maximize v, then minimize s
#define EPI(bits, s) {                                                  \
  uint32_t v = (bits) >> 9;                                             \
  bool gt = v > vmax;                                                   \
  bool eq = v == vmax;                                                  \
  uint32_t sm = smin < (s) ? smin : (s);                                \
  vmax = gt ? v : vmax;                                                 \
  smin = gt ? (s) : (eq ? sm : smin);                                   \
}

// ---------------------------------------------------------------------------
// Kernel 1: compaction with per-block aggregation (1024 blocks per batch).
// ---------------------------------------------------------------------------
__global__ __launch_bounds__(256) void k_compact(const int* __restrict__ mask,
                                                 int* __restrict__ ctr,
                                                 uint32_t* __restrict__ lists) {
  int t = blockIdx.x * 256 + threadIdx.x;           // [0, 2*S_VOL)
  int b = blockIdx.x >> 10;
  int s = t & (S_VOL - 1);
  int z = s >> 12, y = (s >> 6) & 63, x = s & 63;
  int m = mask[t];
  int cnt = 0;
  #pragma unroll
  for (int dz = -1; dz <= 1; ++dz) {
    int zz = z + dz; if (zz < 0 || zz > 63) continue;
    #pragma unroll
    for (int dy = -1; dy <= 1; ++dy) {
      int yy = y + dy; if (yy < 0 || yy > 63) continue;
      #pragma unroll
      for (int dx = -1; dx <= 1; ++dx) {
        int xx = x + dx; if (xx < 0 || xx > 63) continue;
        cnt += mask[(b << 18) + (zz << 12) + (yy << 6) + xx];
      }
    }
  }
  bool pred[4];
  pred[1] = (m == 1);                 // pos
  pred[3] = (m == 0);                 // neg
  pred[0] = pred[1] && (cnt < 27);    // posb
  pred[2] = pred[3] && (cnt > 0);     // negb

  __shared__ int wcnt[4][4];          // [set][wave]
  __shared__ int wbase[4][4];
  int wave = threadIdx.x >> 6;
  int lane = threadIdx.x & 63;
  unsigned long long below = (lane == 63) ? ~0ull : ((1ull << (lane + 1)) - 1ull);
  below >>= 1;                        // bits strictly below lane

  int pre[4];
  #pragma unroll
  for (int set = 0; set < 4; ++set) {
    unsigned long long bv = __ballot(pred[set]);
    if (lane == 0) wcnt[set][wave] = (int)__popcll(bv);
    pre[set] = (int)__popcll(bv & below);
  }
  __syncthreads();
  if (threadIdx.x < 4) {
    int set = threadIdx.x;
    int c0 = wcnt[set][0], c1 = wcnt[set][1], c2 = wcnt[set][2], c3 = wcnt[set][3];
    int tot = c0 + c1 + c2 + c3;
    int base = 0;
    if (tot) base = atomicAdd(&ctr[CTR(b, set)], tot);
    wbase[set][0] = base;
    wbase[set][1] = base + c0;
    wbase[set][2] = base + c0 + c1;
    wbase[set][3] = base + c0 + c1 + c2;
  }
  __syncthreads();

  uint32_t* regA = lists + (size_t)b * (2 * S_VOL);
  uint32_t* regB = regA + S_VOL;
  #pragma unroll
  for (int set = 0; set < 4; ++set) {
    if (pred[set]) {
      int idx = wbase[set][wave] + pre[set];
      uint32_t* reg = (set & 1) ? regB : regA;
      reg[(set < 2) ? idx : (S_VOL - 1 - idx)] = (uint32_t)s;
    }
  }
}

// pad lists to uint4 alignment with duplicate entries (dups can't change max)
__global__ void k_pad(const int* __restrict__ ctr, uint32_t* __restrict__ lists) {
  int i = threadIdx.x;
  if (i >= 8) return;
  int b = i >> 2, set = i & 3;
  uint32_t* regA = lists + (size_t)b * (2 * S_VOL);
  uint32_t* reg = (set & 1) ? regA + S_VOL : regA;
  int cnt = ctr[CTR(b, set)];
  if (cnt == 0 || cnt == S_VOL) return;
  if (set < 2) {                 // front list: pad tail [cnt, roundup4)
    uint32_t v = reg[0];
    for (int q = cnt; q < ((cnt + 3) & ~3); ++q) reg[q] = v;
  } else {                       // back list: pad head [(S-cnt)&~3, S-cnt)
    int st = S_VOL - cnt;
    uint32_t v = reg[st];
    for (int q = (st & ~3); q < st; ++q) reg[q] = v;
  }
}

// ---------------------------------------------------------------------------
// Kernel 2: sampler. One wg per (slot d, chunk); 2048 wgs.
// ---------------------------------------------------------------------------
__global__ __launch_bounds__(256) void k_sample_list(const int* __restrict__ ctr,
                                                     const uint32_t* __restrict__ lists,
                                                     unsigned long long* __restrict__ slots,
                                                     Keys keys) {
  int wg = blockIdx.x;
  int chunk = wg & 1;
  int d = wg >> 1;                       // slot id in [0,1024)
  int c, rem;
  if      (d < 352) { c = 0; rem = d; }
  else if (d < 512) { c = 1; rem = d - 352; }
  else if (d < 864) { c = 2; rem = d - 512; }
  else              { c = 3; rem = d - 864; }
  int n = rem & 15, j = rem >> 4;
  int b = n >> 3;

  // mode: 0=list, 2=valid-arith, 3=all-arith
  int mode = 0, set = 0;
  if (c == 0)      { if (ctr[CTR(b,0)]) set = 0; else if (ctr[CTR(b,1)]) set = 1; else mode = 3; }
  else if (c == 1) { if (ctr[CTR(b,1)]) set = 1; else mode = 2; }
  else if (c == 2) { if (ctr[CTR(b,2)]) set = 2; else if (ctr[CTR(b,3)]) set = 3; else mode = 3; }
  else             { if (ctr[CTR(b,3)]) set = 3; else mode = 2; }

  uint32_t k0 = keys.k[c][0], k1 = keys.k[c][1];
  uint32_t ks2 = k0 ^ k1 ^ 0x1BD11BDAu;
  uint32_t ibase = (uint32_t)(j * 16 + n) * (uint32_t)S_VOL;
  TFC tc;
  tc.x0i = k0; tc.sk1 = ibase + k1;
  tc.a1 = k1;  tc.b1 = ks2 + 1u;
  tc.a2 = ks2; tc.b2 = k0 + 2u;
  tc.a3 = k0;  tc.b3 = k1 + 3u;
  tc.a4 = k1;  tc.b4 = ks2 + 4u;
  tc.a5 = ks2; tc.b5 = k0 + 5u;

  int tid = threadIdx.x;
  uint32_t vmax = 0u, smin = SINF;

  if (mode == 0) {
    const uint32_t* regA = lists + (size_t)b * (2 * S_VOL);
    const uint32_t* reg = (set & 1) ? regA + S_VOL : regA;
    int cnt = ctr[CTR(b, set)];
    const uint32_t* base;
    int len4;
    if (set < 2) { base = reg; len4 = (cnt + 3) >> 2; }
    else { int st = (S_VOL - cnt) & ~3; base = reg + st; len4 = (S_VOL - st) >> 2; }
    const uint4* p4 = (const uint4*)base;

    int qi0 = chunk * 256 + tid;
    int nt = (qi0 < len4) ? (((len4 - 1 - qi0) >> 9) + 1) : 0;
    const uint4* p = p4 + qi0;
    uint4 cv = {0, 0, 0, 0};
    if (nt > 0) cv = *p;
    for (int it = 0; it < nt - 1; ++it) {
      p += 512;
      uint4 nv = *p;                  // provably in-bounds for it < nt-1
      uint32_t ba, bb;
      HASH2(cv.x, cv.y, ba, bb);
      EPI(ba, cv.x); EPI(bb, cv.y);
      HASH2(cv.z, cv.w, ba, bb);
      EPI(ba, cv.z); EPI(bb, cv.w);
      cv = nv;
    }
    if (nt > 0) {
      uint32_t ba, bb;
      HASH2(cv.x, cv.y, ba, bb);
      EPI(ba, cv.x); EPI(bb, cv.y);
      HASH2(cv.z, cv.w, ba, bb);
      EPI(ba, cv.z); EPI(bb, cv.w);
    }
  } else if (mode == 2) {
    for (uint32_t i = (uint32_t)(chunk * 256 + tid); i < VALID_N; i += 512u) {
      uint32_t z = i / 3844u;
      uint32_t r2 = i - z * 3844u;
      uint32_t y = r2 / 62u;
      uint32_t x = r2 - y * 62u;
      uint32_t s = ((z + 1u) << 12) | ((y + 1u) << 6) | (x + 1u);
      uint32_t bits = tf_hash_c(s, tc);
      EPI(bits, s);
    }
  } else {
    for (uint32_t s = (uint32_t)(chunk * 256 + tid); s < S_VOL; s += 512u) {
      uint32_t bits = tf_hash_c(s, tc);
      EPI(bits, s);
    }
  }

  // lexicographic wave reduction on (vmax asc, smin desc-preference)
  #pragma unroll
  for (int off = 32; off; off >>= 1) {
    uint32_t ov = __shfl_down(vmax, off);
    uint32_t os = __shfl_down(smin, off);
    bool take = (ov > vmax) || (ov == vmax && os < smin);
    vmax = take ? ov : vmax;
    smin = take ? os : smin;
  }
  if ((tid & 63) == 0 && smin != SINF) {
    unsigned long long key =
        ((unsigned long long)(vmax + 1u) << 18) |
        (unsigned long long)((S_VOL - 1u) - smin);
    atomicMax(&slots[d], key);
  }
}

// ---------------------------------------------------------------------------
// Kernel 3: gather 3x3x3 patches (replicate pad == clamp).
// ---------------------------------------------------------------------------
__global__ __launch_bounds__(256) void k_gather(const float* __restrict__ fmap,
                                                const unsigned long long* __restrict__ slots,
                                                float* __restrict__ out) {
  int tid = blockIdx.x * 256 + threadIdx.x;
  if (tid >= OUT_N) return;
  int o  = tid % 27;
  int q  = tid / 27;
  int cg = q & 7;   q >>= 3;
  int m  = q & 31;  q >>= 5;
  int t  = q & 1;   q >>= 1;
  int gi = q & 7;
  int b  = q >> 3;
  int n  = b * 8 + gi;
  int slot;
  if (t == 0) slot = (m < 22) ? (m * 16 + n) : (352 + (m - 22) * 16 + n);
  else        slot = (m < 22) ? (512 + m * 16 + n) : (864 + (m - 22) * 16 + n);
  int s = (S_VOL - 1) - (int)(slots[slot] & 0x3FFFFull);
  int z = s >> 12, y = (s >> 6) & 63, x = s & 63;
  int dz = o / 9 - 1, dy = (o / 3) % 3 - 1, dx = o % 3 - 1;
  int zc = min(max(z + dz, 0), 63);
  int yc = min(max(y + dy, 0), 63);
  int xc = min(max(x + dx, 0), 63);
  int ch = gi * 8 + cg;
  out[tid] = fmap[((b * 64 + ch) << 18) + (zc << 12) + (yc << 6) + xc];
}

// ===========================================================================
extern "C" void kernel_launch(void* const* d_in, const int* in_sizes, int n_in,
                              void* d_out, int out_size, void* d_ws, size_t ws_size,
                              hipStream_t stream) {
  const float* fmap = (const float*)d_in[0];
  const int*   mask = (const int*)d_in[1];
  float* out = (float*)d_out;

  int* ctr = (int*)d_ws;                                                 // 8 × 64B
  unsigned long long* slots = (unsigned long long*)((char*)d_ws + 1024); // 1024 u64
  uint32_t* lists = (uint32_t*)((char*)d_ws + 16384);                    // 4*S u32

  // keys = jax.random.split(jax.random.key(42), 4): foldlike, RAW pair output
  Keys K;
  for (int c = 0; c < 4; ++c) {
    uint32_t x0 = 0u, x1 = (uint32_t)c;
    tf2x32(0u, 42u, x0, x1);
    K.k[c][0] = x0; K.k[c][1] = x1;
  }

  hipMemsetAsync(d_ws, 0, 16384, stream);
  hipLaunchKernelGGL(k_compact, dim3(2048), dim3(256), 0, stream, mask, ctr, lists);
  hipLaunchKernelGGL(k_pad, dim3(1), dim3(64), 0, stream, ctr, lists);
  hipLaunchKernelGGL(k_sample_list, dim3(2048), dim3(256), 0, stream, ctr, lists, slots, K);
  hipLaunchKernelGGL(k_gather, dim3((OUT_N + 255) / 256), dim3(256), 0, stream, fmap, slots, out);
}

// Round 6
// 298.314 us; speedup vs baseline: 1.0367x; 1.0367x over previous
//
#include <hip/hip_runtime.h>
#include <stdint.h>

// ============================================================================
// HyperPatch: bit-exact jax.random.categorical (threefry2x32, partitionable)
// + 3x3x3 patch gather.
//
// categorical with 0/1 probs == argmax over allowed s of (threefry_bits>>9),
// tie -> lowest flat index. Slot key: ((val23+1)<<18)|(S-1-s); u64 atomicMax.
//
// Round-6: sampler is saturated VALU-issue-bound (~4 cyc/wave64 int instr
// empirically). Cut instruction count: fold stage-adds into v_add3_u32 at the
// 4 key-schedule boundaries (-4/cand), ping-pong unroll to kill cv=nv movs
// (-1/cand). Exact EPI kept (no probabilistic shortcuts).
//
// ws layout: ctr   @0      int, stride 16 u32 (64B/counter), 8 counters
//            slots @1024   u64[1024]
//            lists @16384  u32[4*S_VOL]:
//              regA(b)=lists+b*2S: posb front, negb back
//              regB(b)=regA+S:     pos  front, neg  back
// ============================================================================

#define S_VOL   262144          // 64*64*64
#define VALID_N 238328          // 62^3
#define OUT_N   221184          // 2*8*1*2*32*8*27
#define CTR(b, set) (((b) * 4 + (set)) * 16)
#define SINF 0xFFFFFFFFu

struct Keys { uint32_t k[4][2]; };

// ---------------- threefry2x32 (reference C version, host + cold paths) -----
#define TF_ROUND(r) { x0 += x1; x1 = (x1 << (r)) | (x1 >> (32 - (r))); x1 ^= x0; }

__host__ __device__ static inline void tf2x32(uint32_t k0, uint32_t k1,
                                              uint32_t& x0, uint32_t& x1) {
  uint32_t ks2 = k0 ^ k1 ^ 0x1BD11BDAu;
  x0 += k0; x1 += k1;
  TF_ROUND(13) TF_ROUND(15) TF_ROUND(26) TF_ROUND(6)
  x0 += k1;  x1 += ks2 + 1u;
  TF_ROUND(17) TF_ROUND(29) TF_ROUND(16) TF_ROUND(24)
  x0 += ks2; x1 += k0 + 2u;
  TF_ROUND(13) TF_ROUND(15) TF_ROUND(26) TF_ROUND(6)
  x0 += k0;  x1 += k1 + 3u;
  TF_ROUND(17) TF_ROUND(29) TF_ROUND(16) TF_ROUND(24)
  x0 += k1;  x1 += ks2 + 4u;
  TF_ROUND(13) TF_ROUND(15) TF_ROUND(26) TF_ROUND(6)
  x0 += ks2; x1 += k0 + 5u;
}

struct TFC { uint32_t x0i, sk1, a1,b1,a2,b2,a3,b3,a4,b4,a5,b5; };

__device__ static inline uint32_t tf_hash_c(uint32_t s, const TFC& c) {
  uint32_t x0 = c.x0i, x1 = s + c.sk1;
  #define RR(r) { x0 += x1; x1 = (x1 << (r)) | (x1 >> (32 - (r))); x1 ^= x0; }
  RR(13) RR(15) RR(26) RR(6)   x0 += c.a1; x1 += c.b1;
  RR(17) RR(29) RR(16) RR(24)  x0 += c.a2; x1 += c.b2;
  RR(13) RR(15) RR(26) RR(6)   x0 += c.a3; x1 += c.b3;
  RR(17) RR(29) RR(16) RR(24)  x0 += c.a4; x1 += c.b4;
  RR(13) RR(15) RR(26) RR(6)   x0 += c.a5; x1 += c.b5;
  #undef RR
  return x0 ^ x1;
}

// 2-chain asm round: rotl(x,r) == v_alignbit_b32(x,x,32-r). 6 instr, ILP-2.
#define RND2(S2) asm("v_add_u32 %0, %0, %1\n\t"                    \
                     "v_add_u32 %2, %2, %3\n\t"                    \
                     "v_alignbit_b32 %1, %1, %1, " #S2 "\n\t"      \
                     "v_alignbit_b32 %3, %3, %3, " #S2 "\n\t"      \
                     "v_xor_b32 %1, %1, %0\n\t"                    \
                     "v_xor_b32 %3, %3, %2"                        \
                     : "+v"(x0a), "+v"(x1a), "+v"(x0b), "+v"(x1b))

// Boundary round: fold stage-adds {x0+=SA; x1+=SB} with the round's x0+=x1
// into v_add3_u32. 8 instr (vs 10 unfused). SA/SB are wave-uniform SGPRs.
#define BND2(S2, SA, SB) asm("v_add_u32 %1, %4, %1\n\t"            \
                     "v_add_u32 %3, %4, %3\n\t"                    \
                     "v_add3_u32 %0, %0, %1, %5\n\t"               \
                     "v_add3_u32 %2, %2, %3, %5\n\t"               \
                     "v_alignbit_b32 %1, %1, %1, " #S2 "\n\t"      \
                     "v_alignbit_b32 %3, %3, %3, " #S2 "\n\t"      \
                     "v_xor_b32 %1, %1, %0\n\t"                    \
                     "v_xor_b32 %3, %3, %2"                        \
                     : "+v"(x0a), "+v"(x1a), "+v"(x0b), "+v"(x1b)  \
                     : "s"(SB), "s"(SA))

// rot {13,15,26,6} -> shifts {19,17,6,26}; rot {17,29,16,24} -> {15,3,16,8}
#define GRP_A3 RND2(17); RND2(6); RND2(26)
#define GRP_B3 RND2(3); RND2(16); RND2(8)

#define HASH2(sa, sb, ba, bb) {                                         \
  uint32_t x0a = tc.x0i, x1a = (sa) + tc.sk1;                           \
  uint32_t x0b = tc.x0i, x1b = (sb) + tc.sk1;                           \
  RND2(19); RND2(17); RND2(6); RND2(26);   /* rounds 1-4  */            \
  BND2(15, tc.a1, tc.b1); GRP_B3;          /* rounds 5-8  */            \
  BND2(19, tc.a2, tc.b2); GRP_A3;          /* rounds 9-12 */            \
  BND2(15, tc.a3, tc.b3); GRP_B3;          /* rounds 13-16*/            \
  BND2(19, tc.a4, tc.b4); GRP_A3;          /* rounds 17-20*/            \
  ba = (x0a + tc.a5) ^ (x1a + tc.b5);                                   \
  bb = (x0b + tc.a5) ^ (x1b + tc.b5);                                   \
}

// 32-bit lexicographic running-max update: maximize v, then minimize s. Exact.
#define EPI(bits, s) {                                                  \
  uint32_t v = (bits) >> 9;                                             \
  bool gt = v > vmax;                                                   \
  bool eq = v == vmax;                                                  \
  uint32_t sm = smin < (s) ? smin : (s);                                \
  vmax = gt ? v : vmax;                                                 \
  smin = gt ? (s) : (eq ? sm : smin);                                   \
}

#define PROC4(cv) {                                                     \
  uint32_t ba, bb;                                                      \
  HASH2((cv).x, (cv).y, ba, bb);                                        \
  EPI(ba, (cv).x); EPI(bb, (cv).y);                                     \
  HASH2((cv).z, (cv).w, ba, bb);                                        \
  EPI(ba, (cv).z); EPI(bb, (cv).w);                                     \
}

__device__ static inline unsigned long long shfl_down_u64(unsigned long long v, int off) {
  uint32_t lo = (uint32_t)v, hi = (uint32_t)(v >> 32);
  lo = __shfl_down(lo, off);
  hi = __shfl_down(hi, off);
  return ((unsigned long long)hi << 32) | lo;
}

// ---------------------------------------------------------------------------
// Kernel 1: compaction with per-block aggregation (1024 blocks per batch).
// ---------------------------------------------------------------------------
__global__ __launch_bounds__(256) void k_compact(const int* __restrict__ mask,
                                                 int* __restrict__ ctr,
                                                 uint32_t* __restrict__ lists) {
  int t = blockIdx.x * 256 + threadIdx.x;           // [0, 2*S_VOL)
  int b = blockIdx.x >> 10;
  int s = t & (S_VOL - 1);
  int z = s >> 12, y = (s >> 6) & 63, x = s & 63;
  int m = mask[t];
  int cnt = 0;
  #pragma unroll
  for (int dz = -1; dz <= 1; ++dz) {
    int zz = z + dz; if (zz < 0 || zz > 63) continue;
    #pragma unroll
    for (int dy = -1; dy <= 1; ++dy) {
      int yy = y + dy; if (yy < 0 || yy > 63) continue;
      #pragma unroll
      for (int dx = -1; dx <= 1; ++dx) {
        int xx = x + dx; if (xx < 0 || xx > 63) continue;
        cnt += mask[(b << 18) + (zz << 12) + (yy << 6) + xx];
      }
    }
  }
  bool pred[4];
  pred[1] = (m == 1);                 // pos
  pred[3] = (m == 0);                 // neg
  pred[0] = pred[1] && (cnt < 27);    // posb
  pred[2] = pred[3] && (cnt > 0);     // negb

  __shared__ int wcnt[4][4];          // [set][wave]
  __shared__ int wbase[4][4];
  int wave = threadIdx.x >> 6;
  int lane = threadIdx.x & 63;
  unsigned long long below = (lane == 63) ? ~0ull : ((1ull << (lane + 1)) - 1ull);
  below >>= 1;                        // bits strictly below lane

  int pre[4];
  #pragma unroll
  for (int set = 0; set < 4; ++set) {
    unsigned long long bv = __ballot(pred[set]);
    if (lane == 0) wcnt[set][wave] = (int)__popcll(bv);
    pre[set] = (int)__popcll(bv & below);
  }
  __syncthreads();
  if (threadIdx.x < 4) {
    int set = threadIdx.x;
    int c0 = wcnt[set][0], c1 = wcnt[set][1], c2 = wcnt[set][2], c3 = wcnt[set][3];
    int tot = c0 + c1 + c2 + c3;
    int base = 0;
    if (tot) base = atomicAdd(&ctr[CTR(b, set)], tot);
    wbase[set][0] = base;
    wbase[set][1] = base + c0;
    wbase[set][2] = base + c0 + c1;
    wbase[set][3] = base + c0 + c1 + c2;
  }
  __syncthreads();

  uint32_t* regA = lists + (size_t)b * (2 * S_VOL);
  uint32_t* regB = regA + S_VOL;
  #pragma unroll
  for (int set = 0; set < 4; ++set) {
    if (pred[set]) {
      int idx = wbase[set][wave] + pre[set];
      uint32_t* reg = (set & 1) ? regB : regA;
      reg[(set < 2) ? idx : (S_VOL - 1 - idx)] = (uint32_t)s;
    }
  }
}

// pad lists to uint4 alignment with duplicate entries (dups can't change max)
__global__ void k_pad(const int* __restrict__ ctr, uint32_t* __restrict__ lists) {
  int i = threadIdx.x;
  if (i >= 8) return;
  int b = i >> 2, set = i & 3;
  uint32_t* regA = lists + (size_t)b * (2 * S_VOL);
  uint32_t* reg = (set & 1) ? regA + S_VOL : regA;
  int cnt = ctr[CTR(b, set)];
  if (cnt == 0 || cnt == S_VOL) return;
  if (set < 2) {                 // front list: pad tail [cnt, roundup4)
    uint32_t v = reg[0];
    for (int q = cnt; q < ((cnt + 3) & ~3); ++q) reg[q] = v;
  } else {                       // back list: pad head [(S-cnt)&~3, S-cnt)
    int st = S_VOL - cnt;
    uint32_t v = reg[st];
    for (int q = (st & ~3); q < st; ++q) reg[q] = v;
  }
}

// ---------------------------------------------------------------------------
// Kernel 2: sampler. One wg per (slot d, chunk); 2048 wgs.
// ---------------------------------------------------------------------------
__global__ __launch_bounds__(256) void k_sample_list(const int* __restrict__ ctr,
                                                     const uint32_t* __restrict__ lists,
                                                     unsigned long long* __restrict__ slots,
                                                     Keys keys) {
  int wg = blockIdx.x;
  int chunk = wg & 1;
  int d = wg >> 1;                       // slot id in [0,1024)
  int c, rem;
  if      (d < 352) { c = 0; rem = d; }
  else if (d < 512) { c = 1; rem = d - 352; }
  else if (d < 864) { c = 2; rem = d - 512; }
  else              { c = 3; rem = d - 864; }
  int n = rem & 15, j = rem >> 4;
  int b = n >> 3;

  // mode: 0=list, 2=valid-arith, 3=all-arith
  int mode = 0, set = 0;
  if (c == 0)      { if (ctr[CTR(b,0)]) set = 0; else if (ctr[CTR(b,1)]) set = 1; else mode = 3; }
  else if (c == 1) { if (ctr[CTR(b,1)]) set = 1; else mode = 2; }
  else if (c == 2) { if (ctr[CTR(b,2)]) set = 2; else if (ctr[CTR(b,3)]) set = 3; else mode = 3; }
  else             { if (ctr[CTR(b,3)]) set = 3; else mode = 2; }

  uint32_t k0 = keys.k[c][0], k1 = keys.k[c][1];
  uint32_t ks2 = k0 ^ k1 ^ 0x1BD11BDAu;
  uint32_t ibase = (uint32_t)(j * 16 + n) * (uint32_t)S_VOL;
  TFC tc;
  tc.x0i = k0; tc.sk1 = ibase + k1;
  tc.a1 = k1;  tc.b1 = ks2 + 1u;
  tc.a2 = ks2; tc.b2 = k0 + 2u;
  tc.a3 = k0;  tc.b3 = k1 + 3u;
  tc.a4 = k1;  tc.b4 = ks2 + 4u;
  tc.a5 = ks2; tc.b5 = k0 + 5u;

  int tid = threadIdx.x;
  uint32_t vmax = 0u, smin = SINF;

  if (mode == 0) {
    const uint32_t* regA = lists + (size_t)b * (2 * S_VOL);
    const uint32_t* reg = (set & 1) ? regA + S_VOL : regA;
    int cnt = ctr[CTR(b, set)];
    const uint32_t* base;
    int len4;
    if (set < 2) { base = reg; len4 = (cnt + 3) >> 2; }
    else { int st = (S_VOL - cnt) & ~3; base = reg + st; len4 = (S_VOL - st) >> 2; }
    const uint4* p4 = (const uint4*)base;

    int qi0 = chunk * 256 + tid;
    int nt = (qi0 < len4) ? (((len4 - 1 - qi0) >> 9) + 1) : 0;
    uint32_t off = (uint32_t)qi0;          // in uint4 units, stride 512
    uint4 a, bq;
    int it = 0;
    if (nt > 0) a = p4[off];
    // ping-pong 2x unroll, prefetch distance 1, no register copies
    for (; it + 1 < nt - 1; it += 2) {
      bq = p4[off + 512];
      PROC4(a);
      a = p4[off + 1024];
      PROC4(bq);
      off += 1024;
    }
    if (it == nt - 2) {
      bq = p4[off + 512];
      PROC4(a);
      PROC4(bq);
    } else if (it == nt - 1) {
      PROC4(a);
    }
  } else if (mode == 2) {
    for (uint32_t i = (uint32_t)(chunk * 256 + tid); i < VALID_N; i += 512u) {
      uint32_t z = i / 3844u;
      uint32_t r2 = i - z * 3844u;
      uint32_t y = r2 / 62u;
      uint32_t x = r2 - y * 62u;
      uint32_t s = ((z + 1u) << 12) | ((y + 1u) << 6) | (x + 1u);
      uint32_t bits = tf_hash_c(s, tc);
      EPI(bits, s);
    }
  } else {
    for (uint32_t s = (uint32_t)(chunk * 256 + tid); s < S_VOL; s += 512u) {
      uint32_t bits = tf_hash_c(s, tc);
      EPI(bits, s);
    }
  }

  // lexicographic wave reduction on (vmax max, smin min)
  #pragma unroll
  for (int off2 = 32; off2; off2 >>= 1) {
    uint32_t ov = __shfl_down(vmax, off2);
    uint32_t os = __shfl_down(smin, off2);
    bool take = (ov > vmax) || (ov == vmax && os < smin);
    vmax = take ? ov : vmax;
    smin = take ? os : smin;
  }
  if ((tid & 63) == 0 && smin != SINF) {
    unsigned long long key =
        ((unsigned long long)(vmax + 1u) << 18) |
        (unsigned long long)((S_VOL - 1u) - smin);
    atomicMax(&slots[d], key);
  }
}

// ---------------------------------------------------------------------------
// Kernel 3: gather 3x3x3 patches (replicate pad == clamp).
// ---------------------------------------------------------------------------
__global__ __launch_bounds__(256) void k_gather(const float* __restrict__ fmap,
                                                const unsigned long long* __restrict__ slots,
                                                float* __restrict__ out) {
  int tid = blockIdx.x * 256 + threadIdx.x;
  if (tid >= OUT_N) return;
  int o  = tid % 27;
  int q  = tid / 27;
  int cg = q & 7;   q >>= 3;
  int m  = q & 31;  q >>= 5;
  int t  = q & 1;   q >>= 1;
  int gi = q & 7;
  int b  = q >> 3;
  int n  = b * 8 + gi;
  int slot;
  if (t == 0) slot = (m < 22) ? (m * 16 + n) : (352 + (m - 22) * 16 + n);
  else        slot = (m < 22) ? (512 + m * 16 + n) : (864 + (m - 22) * 16 + n);
  int s = (S_VOL - 1) - (int)(slots[slot] & 0x3FFFFull);
  int z = s >> 12, y = (s >> 6) & 63, x = s & 63;
  int dz = o / 9 - 1, dy = (o / 3) % 3 - 1, dx = o % 3 - 1;
  int zc = min(max(z + dz, 0), 63);
  int yc = min(max(y + dy, 0), 63);
  int xc = min(max(x + dx, 0), 63);
  int ch = gi * 8 + cg;
  out[tid] = fmap[((b * 64 + ch) << 18) + (zc << 12) + (yc << 6) + xc];
}

// ===========================================================================
extern "C" void kernel_launch(void* const* d_in, const int* in_sizes, int n_in,
                              void* d_out, int out_size, void* d_ws, size_t ws_size,
                              hipStream_t stream) {
  const float* fmap = (const float*)d_in[0];
  const int*   mask = (const int*)d_in[1];
  float* out = (float*)d_out;

  int* ctr = (int*)d_ws;                                                 // 8 × 64B
  unsigned long long* slots = (unsigned long long*)((char*)d_ws + 1024); // 1024 u64
  uint32_t* lists = (uint32_t*)((char*)d_ws + 16384);                    // 4*S u32

  // keys = jax.random.split(jax.random.key(42), 4): foldlike, RAW pair output
  Keys K;
  for (int c = 0; c < 4; ++c) {
    uint32_t x0 = 0u, x1 = (uint32_t)c;
    tf2x32(0u, 42u, x0, x1);
    K.k[c][0] = x0; K.k[c][1] = x1;
  }

  hipMemsetAsync(d_ws, 0, 16384, stream);
  hipLaunchKernelGGL(k_compact, dim3(2048), dim3(256), 0, stream, mask, ctr, lists);
  hipLaunchKernelGGL(k_pad, dim3(1), dim3(64), 0, stream, ctr, lists);
  hipLaunchKernelGGL(k_sample_list, dim3(2048), dim3(256), 0, stream, ctr, lists, slots, K);
  hipLaunchKernelGGL(k_gather, dim3((OUT_N + 255) / 256), dim3(256), 0, stream, fmap, slots, out);
}

// Round 7
// 271.082 us; speedup vs baseline: 1.1409x; 1.1005x over previous
//
#include <hip/hip_runtime.h>
#include <stdint.h>

// ============================================================================
// HyperPatch: bit-exact jax.random.categorical (threefry2x32, partitionable)
// + 3x3x3 patch gather.
//
// categorical with 0/1 probs == argmax over allowed s of (threefry_bits>>9),
// tie -> lowest flat index. Slot key: ((val23+1)<<18)|(S-1-s); u64 atomicMax.
//
// Round-7: sampler time was invariant under instr cuts (R4-R6: ~290us at
// 93->77 instr/cand, VALUBusy ~99%) => ~4cyc/wave64 int instr effective.
// Cut the non-hash tail: per-candidate EPI (7 instr) -> 1 v_cmp against a
// wave-uniform threshold thr9 = wave_max(vmax)<<9 (bits >= v<<9 <=> bits>>9
// >= v); exact EPI runs only on rare wave triggers (+butterfly rebuild).
// Fold round-1: x0_1 = s + (x0i+sk1) kills the x0i movs.
//
// ws layout: ctr   @0      int, stride 16 u32 (64B/counter), 8 counters
//            slots @1024   u64[1024]
//            lists @16384  u32[4*S_VOL]:
//              regA(b)=lists+b*2S: posb front, negb back
//              regB(b)=regA+S:     pos  front, neg  back
// ============================================================================

#define S_VOL   262144          // 64*64*64
#define VALID_N 238328          // 62^3
#define OUT_N   221184          // 2*8*1*2*32*8*27
#define CTR(b, set) (((b) * 4 + (set)) * 16)
#define SINF 0xFFFFFFFFu

struct Keys { uint32_t k[4][2]; };

// ---------------- threefry2x32 (reference C version, host + cold paths) -----
#define TF_ROUND(r) { x0 += x1; x1 = (x1 << (r)) | (x1 >> (32 - (r))); x1 ^= x0; }

__host__ __device__ static inline void tf2x32(uint32_t k0, uint32_t k1,
                                              uint32_t& x0, uint32_t& x1) {
  uint32_t ks2 = k0 ^ k1 ^ 0x1BD11BDAu;
  x0 += k0; x1 += k1;
  TF_ROUND(13) TF_ROUND(15) TF_ROUND(26) TF_ROUND(6)
  x0 += k1;  x1 += ks2 + 1u;
  TF_ROUND(17) TF_ROUND(29) TF_ROUND(16) TF_ROUND(24)
  x0 += ks2; x1 += k0 + 2u;
  TF_ROUND(13) TF_ROUND(15) TF_ROUND(26) TF_ROUND(6)
  x0 += k0;  x1 += k1 + 3u;
  TF_ROUND(17) TF_ROUND(29) TF_ROUND(16) TF_ROUND(24)
  x0 += k1;  x1 += ks2 + 4u;
  TF_ROUND(13) TF_ROUND(15) TF_ROUND(26) TF_ROUND(6)
  x0 += ks2; x1 += k0 + 5u;
}

struct TFC { uint32_t x0i, sk1, c0, a1,b1,a2,b2,a3,b3,a4,b4,a5,b5; };

__device__ static inline uint32_t tf_hash_c(uint32_t s, const TFC& c) {
  uint32_t x0 = c.x0i, x1 = s + c.sk1;
  #define RR(r) { x0 += x1; x1 = (x1 << (r)) | (x1 >> (32 - (r))); x1 ^= x0; }
  RR(13) RR(15) RR(26) RR(6)   x0 += c.a1; x1 += c.b1;
  RR(17) RR(29) RR(16) RR(24)  x0 += c.a2; x1 += c.b2;
  RR(13) RR(15) RR(26) RR(6)   x0 += c.a3; x1 += c.b3;
  RR(17) RR(29) RR(16) RR(24)  x0 += c.a4; x1 += c.b4;
  RR(13) RR(15) RR(26) RR(6)   x0 += c.a5; x1 += c.b5;
  #undef RR
  return x0 ^ x1;
}

// 2-chain asm round: rotl(x,r) == v_alignbit_b32(x,x,32-r). 6 instr, ILP-2.
#define RND2(S2) asm("v_add_u32 %0, %0, %1\n\t"                    \
                     "v_add_u32 %2, %2, %3\n\t"                    \
                     "v_alignbit_b32 %1, %1, %1, " #S2 "\n\t"      \
                     "v_alignbit_b32 %3, %3, %3, " #S2 "\n\t"      \
                     "v_xor_b32 %1, %1, %0\n\t"                    \
                     "v_xor_b32 %3, %3, %2"                        \
                     : "+v"(x0a), "+v"(x1a), "+v"(x0b), "+v"(x1b))

// Boundary round: fold stage-adds {x0+=SA; x1+=SB} with the round's x0+=x1
// into v_add3_u32. 8 instr. SA/SB are wave-uniform SGPRs (1 sgpr read/instr).
#define BND2(S2, SA, SB) asm("v_add_u32 %1, %4, %1\n\t"            \
                     "v_add_u32 %3, %4, %3\n\t"                    \
                     "v_add3_u32 %0, %0, %1, %5\n\t"               \
                     "v_add3_u32 %2, %2, %3, %5\n\t"               \
                     "v_alignbit_b32 %1, %1, %1, " #S2 "\n\t"      \
                     "v_alignbit_b32 %3, %3, %3, " #S2 "\n\t"      \
                     "v_xor_b32 %1, %1, %0\n\t"                    \
                     "v_xor_b32 %3, %3, %2"                        \
                     : "+v"(x0a), "+v"(x1a), "+v"(x0b), "+v"(x1b)  \
                     : "s"(SB), "s"(SA))

// rot {13,15,26,6} -> shifts {19,17,6,26}; rot {17,29,16,24} -> {15,3,16,8}
#define GRP_A3 RND2(17); RND2(6); RND2(26)
#define GRP_B3 RND2(3); RND2(16); RND2(8)

// Fused init + round 1: x0_1 = s + (x0i+sk1) [=c0], x1_0 = s + sk1,
// then rot(13)+xor. 8 instr for both chains (vs 10).
#define HASH2F(sa, sb, ba, bb) {                                        \
  uint32_t x0a, x1a, x0b, x1b;                                          \
  asm("v_add_u32 %0, %4, %6\n\t"                                        \
      "v_add_u32 %1, %5, %6\n\t"                                        \
      "v_add_u32 %2, %4, %7\n\t"                                        \
      "v_add_u32 %3, %5, %7\n\t"                                        \
      "v_alignbit_b32 %1, %1, %1, 19\n\t"                               \
      "v_alignbit_b32 %3, %3, %3, 19\n\t"                               \
      "v_xor_b32 %1, %1, %0\n\t"                                        \
      "v_xor_b32 %3, %3, %2"                                            \
      : "=v"(x0a), "=v"(x1a), "=v"(x0b), "=v"(x1b)                      \
      : "s"(tc.c0), "s"(tc.sk1), "v"(sa), "v"(sb));                     \
  RND2(17); RND2(6); RND2(26);             /* rounds 2-4  */            \
  BND2(15, tc.a1, tc.b1); GRP_B3;          /* rounds 5-8  */            \
  BND2(19, tc.a2, tc.b2); GRP_A3;          /* rounds 9-12 */            \
  BND2(15, tc.a3, tc.b3); GRP_B3;          /* rounds 13-16*/            \
  BND2(19, tc.a4, tc.b4); GRP_A3;          /* rounds 17-20*/            \
  ba = (x0a + tc.a5) ^ (x1a + tc.b5);                                   \
  bb = (x0b + tc.a5) ^ (x1b + tc.b5);                                   \
}

// 32-bit lexicographic running-max update: maximize v, then minimize s. Exact.
#define EPI(bits, s) {                                                  \
  uint32_t v = (bits) >> 9;                                             \
  bool gt = v > vmax;                                                   \
  bool eq = v == vmax;                                                  \
  uint32_t sm = smin < (s) ? smin : (s);                                \
  vmax = gt ? v : vmax;                                                 \
  smin = gt ? (s) : (eq ? sm : smin);                                   \
}

// Threshold-gated pair: 1 cmp/cand fast path; exact EPI + threshold rebuild
// on rare wave-level trigger. Skip is strict (bits < wm<<9 <=> v < wm), so
// skipped candidates can neither beat nor tie the final max. Exact.
#define PROC2T(sa, sb) {                                                \
  uint32_t ba, bb;                                                      \
  HASH2F(sa, sb, ba, bb);                                               \
  if (__any((ba >= thr9) || (bb >= thr9))) {                            \
    EPI(ba, sa); EPI(bb, sb);                                           \
    uint32_t wm = vmax;                                                 \
    wm = max(wm, (uint32_t)__shfl_xor(wm, 32));                         \
    wm = max(wm, (uint32_t)__shfl_xor(wm, 16));                         \
    wm = max(wm, (uint32_t)__shfl_xor(wm, 8));                          \
    wm = max(wm, (uint32_t)__shfl_xor(wm, 4));                          \
    wm = max(wm, (uint32_t)__shfl_xor(wm, 2));                          \
    wm = max(wm, (uint32_t)__shfl_xor(wm, 1));                          \
    thr9 = wm << 9;                                                     \
  }                                                                     \
}

#define PROC4T(cv) { PROC2T((cv).x, (cv).y); PROC2T((cv).z, (cv).w); }

// ---------------------------------------------------------------------------
// Kernel 1: compaction with per-block aggregation (1024 blocks per batch).
// ---------------------------------------------------------------------------
__global__ __launch_bounds__(256) void k_compact(const int* __restrict__ mask,
                                                 int* __restrict__ ctr,
                                                 uint32_t* __restrict__ lists) {
  int t = blockIdx.x * 256 + threadIdx.x;           // [0, 2*S_VOL)
  int b = blockIdx.x >> 10;
  int s = t & (S_VOL - 1);
  int z = s >> 12, y = (s >> 6) & 63, x = s & 63;
  int m = mask[t];
  int cnt = 0;
  #pragma unroll
  for (int dz = -1; dz <= 1; ++dz) {
    int zz = z + dz; if (zz < 0 || zz > 63) continue;
    #pragma unroll
    for (int dy = -1; dy <= 1; ++dy) {
      int yy = y + dy; if (yy < 0 || yy > 63) continue;
      #pragma unroll
      for (int dx = -1; dx <= 1; ++dx) {
        int xx = x + dx; if (xx < 0 || xx > 63) continue;
        cnt += mask[(b << 18) + (zz << 12) + (yy << 6) + xx];
      }
    }
  }
  bool pred[4];
  pred[1] = (m == 1);                 // pos
  pred[3] = (m == 0);                 // neg
  pred[0] = pred[1] && (cnt < 27);    // posb
  pred[2] = pred[3] && (cnt > 0);     // negb

  __shared__ int wcnt[4][4];          // [set][wave]
  __shared__ int wbase[4][4];
  int wave = threadIdx.x >> 6;
  int lane = threadIdx.x & 63;
  unsigned long long below = (lane == 63) ? ~0ull : ((1ull << (lane + 1)) - 1ull);
  below >>= 1;                        // bits strictly below lane

  int pre[4];
  #pragma unroll
  for (int set = 0; set < 4; ++set) {
    unsigned long long bv = __ballot(pred[set]);
    if (lane == 0) wcnt[set][wave] = (int)__popcll(bv);
    pre[set] = (int)__popcll(bv & below);
  }
  __syncthreads();
  if (threadIdx.x < 4) {
    int set = threadIdx.x;
    int c0 = wcnt[set][0], c1 = wcnt[set][1], c2 = wcnt[set][2], c3 = wcnt[set][3];
    int tot = c0 + c1 + c2 + c3;
    int base = 0;
    if (tot) base = atomicAdd(&ctr[CTR(b, set)], tot);
    wbase[set][0] = base;
    wbase[set][1] = base + c0;
    wbase[set][2] = base + c0 + c1;
    wbase[set][3] = base + c0 + c1 + c2;
  }
  __syncthreads();

  uint32_t* regA = lists + (size_t)b * (2 * S_VOL);
  uint32_t* regB = regA + S_VOL;
  #pragma unroll
  for (int set = 0; set < 4; ++set) {
    if (pred[set]) {
      int idx = wbase[set][wave] + pre[set];
      uint32_t* reg = (set & 1) ? regB : regA;
      reg[(set < 2) ? idx : (S_VOL - 1 - idx)] = (uint32_t)s;
    }
  }
}

// pad lists to uint4 alignment with duplicate entries (dups can't change max)
__global__ void k_pad(const int* __restrict__ ctr, uint32_t* __restrict__ lists) {
  int i = threadIdx.x;
  if (i >= 8) return;
  int b = i >> 2, set = i & 3;
  uint32_t* regA = lists + (size_t)b * (2 * S_VOL);
  uint32_t* reg = (set & 1) ? regA + S_VOL : regA;
  int cnt = ctr[CTR(b, set)];
  if (cnt == 0 || cnt == S_VOL) return;
  if (set < 2) {                 // front list: pad tail [cnt, roundup4)
    uint32_t v = reg[0];
    for (int q = cnt; q < ((cnt + 3) & ~3); ++q) reg[q] = v;
  } else {                       // back list: pad head [(S-cnt)&~3, S-cnt)
    int st = S_VOL - cnt;
    uint32_t v = reg[st];
    for (int q = (st & ~3); q < st; ++q) reg[q] = v;
  }
}

// ---------------------------------------------------------------------------
// Kernel 2: sampler. One wg per (slot d, chunk); 2048 wgs.
// ---------------------------------------------------------------------------
__global__ __launch_bounds__(256) void k_sample_list(const int* __restrict__ ctr,
                                                     const uint32_t* __restrict__ lists,
                                                     unsigned long long* __restrict__ slots,
                                                     Keys keys) {
  int wg = blockIdx.x;
  int chunk = wg & 1;
  int d = wg >> 1;                       // slot id in [0,1024)
  int c, rem;
  if      (d < 352) { c = 0; rem = d; }
  else if (d < 512) { c = 1; rem = d - 352; }
  else if (d < 864) { c = 2; rem = d - 512; }
  else              { c = 3; rem = d - 864; }
  int n = rem & 15, j = rem >> 4;
  int b = n >> 3;

  // mode: 0=list, 2=valid-arith, 3=all-arith
  int mode = 0, set = 0;
  if (c == 0)      { if (ctr[CTR(b,0)]) set = 0; else if (ctr[CTR(b,1)]) set = 1; else mode = 3; }
  else if (c == 1) { if (ctr[CTR(b,1)]) set = 1; else mode = 2; }
  else if (c == 2) { if (ctr[CTR(b,2)]) set = 2; else if (ctr[CTR(b,3)]) set = 3; else mode = 3; }
  else             { if (ctr[CTR(b,3)]) set = 3; else mode = 2; }

  uint32_t k0 = keys.k[c][0], k1 = keys.k[c][1];
  uint32_t ks2 = k0 ^ k1 ^ 0x1BD11BDAu;
  uint32_t ibase = (uint32_t)(j * 16 + n) * (uint32_t)S_VOL;
  TFC tc;
  tc.x0i = k0; tc.sk1 = ibase + k1; tc.c0 = k0 + tc.sk1;
  tc.a1 = k1;  tc.b1 = ks2 + 1u;
  tc.a2 = ks2; tc.b2 = k0 + 2u;
  tc.a3 = k0;  tc.b3 = k1 + 3u;
  tc.a4 = k1;  tc.b4 = ks2 + 4u;
  tc.a5 = ks2; tc.b5 = k0 + 5u;

  int tid = threadIdx.x;
  uint32_t vmax = 0u, smin = SINF, thr9 = 0u;

  if (mode == 0) {
    const uint32_t* regA = lists + (size_t)b * (2 * S_VOL);
    const uint32_t* reg = (set & 1) ? regA + S_VOL : regA;
    int cnt = ctr[CTR(b, set)];
    const uint32_t* base;
    int len4;
    if (set < 2) { base = reg; len4 = (cnt + 3) >> 2; }
    else { int st = (S_VOL - cnt) & ~3; base = reg + st; len4 = (S_VOL - st) >> 2; }
    const uint4* p4 = (const uint4*)base;

    int qi0 = chunk * 256 + tid;
    int nt = (qi0 < len4) ? (((len4 - 1 - qi0) >> 9) + 1) : 0;
    uint32_t off = (uint32_t)qi0;          // in uint4 units, stride 512
    uint4 a, bq;
    int it = 0;
    if (nt > 0) a = p4[off];
    // ping-pong 2x unroll, prefetch distance 1, no register copies
    for (; it + 1 < nt - 1; it += 2) {
      bq = p4[off + 512];
      PROC4T(a);
      a = p4[off + 1024];
      PROC4T(bq);
      off += 1024;
    }
    if (it == nt - 2) {
      bq = p4[off + 512];
      PROC4T(a);
      PROC4T(bq);
    } else if (it == nt - 1) {
      PROC4T(a);
    }
  } else if (mode == 2) {
    for (uint32_t i = (uint32_t)(chunk * 256 + tid); i < VALID_N; i += 512u) {
      uint32_t z = i / 3844u;
      uint32_t r2 = i - z * 3844u;
      uint32_t y = r2 / 62u;
      uint32_t x = r2 - y * 62u;
      uint32_t s = ((z + 1u) << 12) | ((y + 1u) << 6) | (x + 1u);
      uint32_t bits = tf_hash_c(s, tc);
      EPI(bits, s);
    }
  } else {
    for (uint32_t s = (uint32_t)(chunk * 256 + tid); s < S_VOL; s += 512u) {
      uint32_t bits = tf_hash_c(s, tc);
      EPI(bits, s);
    }
  }

  // lexicographic wave reduction on (vmax max, smin min)
  #pragma unroll
  for (int off2 = 32; off2; off2 >>= 1) {
    uint32_t ov = __shfl_down(vmax, off2);
    uint32_t os = __shfl_down(smin, off2);
    bool take = (ov > vmax) || (ov == vmax && os < smin);
    vmax = take ? ov : vmax;
    smin = take ? os : smin;
  }
  if ((tid & 63) == 0 && smin != SINF) {
    unsigned long long key =
        ((unsigned long long)(vmax + 1u) << 18) |
        (unsigned long long)((S_VOL - 1u) - smin);
    atomicMax(&slots[d], key);
  }
}

// ---------------------------------------------------------------------------
// Kernel 3: gather 3x3x3 patches (replicate pad == clamp).
// ---------------------------------------------------------------------------
__global__ __launch_bounds__(256) void k_gather(const float* __restrict__ fmap,
                                                const unsigned long long* __restrict__ slots,
                                                float* __restrict__ out) {
  int tid = blockIdx.x * 256 + threadIdx.x;
  if (tid >= OUT_N) return;
  int o  = tid % 27;
  int q  = tid / 27;
  int cg = q & 7;   q >>= 3;
  int m  = q & 31;  q >>= 5;
  int t  = q & 1;   q >>= 1;
  int gi = q & 7;
  int b  = q >> 3;
  int n  = b * 8 + gi;
  int slot;
  if (t == 0) slot = (m < 22) ? (m * 16 + n) : (352 + (m - 22) * 16 + n);
  else        slot = (m < 22) ? (512 + m * 16 + n) : (864 + (m - 22) * 16 + n);
  int s = (S_VOL - 1) - (int)(slots[slot] & 0x3FFFFull);
  int z = s >> 12, y = (s >> 6) & 63, x = s & 63;
  int dz = o / 9 - 1, dy = (o / 3) % 3 - 1, dx = o % 3 - 1;
  int zc = min(max(z + dz, 0), 63);
  int yc = min(max(y + dy, 0), 63);
  int xc = min(max(x + dx, 0), 63);
  int ch = gi * 8 + cg;
  out[tid] = fmap[((b * 64 + ch) << 18) + (zc << 12) + (yc << 6) + xc];
}

// ===========================================================================
extern "C" void kernel_launch(void* const* d_in, const int* in_sizes, int n_in,
                              void* d_out, int out_size, void* d_ws, size_t ws_size,
                              hipStream_t stream) {
  const float* fmap = (const float*)d_in[0];
  const int*   mask = (const int*)d_in[1];
  float* out = (float*)d_out;

  int* ctr = (int*)d_ws;                                                 // 8 × 64B
  unsigned long long* slots = (unsigned long long*)((char*)d_ws + 1024); // 1024 u64
  uint32_t* lists = (uint32_t*)((char*)d_ws + 16384);                    // 4*S u32

  // keys = jax.random.split(jax.random.key(42), 4): foldlike, RAW pair output
  Keys K;
  for (int c = 0; c < 4; ++c) {
    uint32_t x0 = 0u, x1 = (uint32_t)c;
    tf2x32(0u, 42u, x0, x1);
    K.k[c][0] = x0; K.k[c][1] = x1;
  }

  hipMemsetAsync(d_ws, 0, 16384, stream);
  hipLaunchKernelGGL(k_compact, dim3(2048), dim3(256), 0, stream, mask, ctr, lists);
  hipLaunchKernelGGL(k_pad, dim3(1), dim3(64), 0, stream, ctr, lists);
  hipLaunchKernelGGL(k_sample_list, dim3(2048), dim3(256), 0, stream, ctr, lists, slots, K);
  hipLaunchKernelGGL(k_gather, dim3((OUT_N + 255) / 256), dim3(256), 0, stream, fmap, slots, out);
}